// Round 13
// baseline (420.458 us; speedup 1.0000x reference)
//
#include <hip/hip_runtime.h>
#include <hip/hip_fp16.h>
#include <hip/hip_cooperative_groups.h>

namespace cg = cooperative_groups;

#define NBUCK 512   // dst-range buckets; R = ceil(N/NBUCK) <= 256
#define CH    4096  // edges per hist/scatter virtual block
#define CAP   4096  // pairs capacity per bucket (mean fill ~2344)
#define VTOT  1024  // virtual blocks in phase A (HB hist + VTOT-HB gemm1)

typedef _Float16 half8 __attribute__((ext_vector_type(8)));
typedef float floatx4 __attribute__((ext_vector_type(4)));

struct Params {
    const int* src;
    const int* dst;
    const float* x;
    const float* W1;
    const float* b1;
    const float* W2;
    const float* b2;
    float* out;
    int* baseTbl;
    int* cursor;
    unsigned long long* pairs;
    int* ssrc;
    int* counts;
    int* offs;
    float* dinv;
    __half* h;     // N*64 fp16
    __half* out1;  // N*64 fp16
    __half* h2;    // N*32 fp16 (aliases h)
    int N, E, R, HB, ntiles;
};

__device__ inline void unpack8(const float4& raw, float* f) {
    const __half2* p = (const __half2*)&raw;
#pragma unroll
    for (int i = 0; i < 4; ++i) {
        float2 t = __half22float2(p[i]);
        f[2 * i] = t.x;
        f[2 * i + 1] = t.y;
    }
}

// ---- gemm1 body: X(M x 64) fp32 @ W1(64 x 64) -> fp16 ----
__device__ void gemm1_body(const float* __restrict__ X, const float* __restrict__ W,
                           __half* __restrict__ H, int M, int ntiles, int vblk, int GB) {
    const int lane = threadIdx.x & 63;
    const int wid  = threadIdx.x >> 6;
    const int q    = lane >> 4;
    const int m    = lane & 15;

    half8 bfrag[2][4];
#pragma unroll
    for (int s = 0; s < 2; ++s)
#pragma unroll
        for (int c = 0; c < 4; ++c)
#pragma unroll
            for (int j = 0; j < 8; ++j)
                bfrag[s][c][j] = (_Float16)W[(s * 32 + q * 8 + j) * 64 + c * 16 + m];

    for (int tile = vblk * 4 + wid; tile < ntiles; tile += GB * 4) {
        int rowBase = tile * 16;
        int rowA = rowBase + m;
        if (rowA > M - 1) rowA = M - 1;
        const float4* Xr = (const float4*)(X + (size_t)rowA * 64);
        half8 afrag[2];
#pragma unroll
        for (int s = 0; s < 2; ++s) {
            float4 v0 = Xr[s * 8 + q * 2 + 0];
            float4 v1 = Xr[s * 8 + q * 2 + 1];
            afrag[s][0] = (_Float16)v0.x; afrag[s][1] = (_Float16)v0.y;
            afrag[s][2] = (_Float16)v0.z; afrag[s][3] = (_Float16)v0.w;
            afrag[s][4] = (_Float16)v1.x; afrag[s][5] = (_Float16)v1.y;
            afrag[s][6] = (_Float16)v1.z; afrag[s][7] = (_Float16)v1.w;
        }
        floatx4 acc[4];
#pragma unroll
        for (int c = 0; c < 4; ++c) acc[c] = (floatx4){0.f, 0.f, 0.f, 0.f};
#pragma unroll
        for (int s = 0; s < 2; ++s)
#pragma unroll
            for (int c = 0; c < 4; ++c)
                acc[c] = __builtin_amdgcn_mfma_f32_16x16x32_f16(afrag[s], bfrag[s][c], acc[c],
                                                                0, 0, 0);
#pragma unroll
        for (int r = 0; r < 4; ++r) {
            int row = rowBase + q * 4 + r;
            if (row < M) {
#pragma unroll
                for (int c = 0; c < 4; ++c)
                    H[(size_t)row * 64 + c * 16 + m] = __float2half(acc[c][r]);
            }
        }
    }
}

// ---- gemm2 body: X(M x 64) fp16 @ W2(64 x 32) -> fp16 ----
__device__ void gemm2_body(const __half* __restrict__ X, const float* __restrict__ W,
                           __half* __restrict__ H, int M, int ntiles, int vblk, int GB) {
    const int lane = threadIdx.x & 63;
    const int wid  = threadIdx.x >> 6;
    const int q    = lane >> 4;
    const int m    = lane & 15;

    half8 bfrag[2][2];
#pragma unroll
    for (int s = 0; s < 2; ++s)
#pragma unroll
        for (int c = 0; c < 2; ++c)
#pragma unroll
            for (int j = 0; j < 8; ++j)
                bfrag[s][c][j] = (_Float16)W[(s * 32 + q * 8 + j) * 32 + c * 16 + m];

    for (int tile = vblk * 4 + wid; tile < ntiles; tile += GB * 4) {
        int rowBase = tile * 16;
        int rowA = rowBase + m;
        if (rowA > M - 1) rowA = M - 1;
        const half8* Xr = (const half8*)(X + (size_t)rowA * 64);
        half8 afrag[2];
#pragma unroll
        for (int s = 0; s < 2; ++s) afrag[s] = Xr[s * 4 + q];
        floatx4 acc[2];
#pragma unroll
        for (int c = 0; c < 2; ++c) acc[c] = (floatx4){0.f, 0.f, 0.f, 0.f};
#pragma unroll
        for (int s = 0; s < 2; ++s)
#pragma unroll
            for (int c = 0; c < 2; ++c)
                acc[c] = __builtin_amdgcn_mfma_f32_16x16x32_f16(afrag[s], bfrag[s][c], acc[c],
                                                                0, 0, 0);
#pragma unroll
        for (int r = 0; r < 4; ++r) {
            int row = rowBase + q * 4 + r;
            if (row < M) {
#pragma unroll
                for (int c = 0; c < 2; ++c)
                    H[(size_t)row * 32 + c * 16 + m] = __float2half(acc[c][r]);
            }
        }
    }
}

// ---- phase: block-local dst histogram + atomic chunk reserve ----
__device__ void phase_hist(const Params& p, int vb) {
    __shared__ int h[NBUCK];
    int tid = threadIdx.x;
    __syncthreads();  // LDS reuse guard across grid-stride iterations
    for (int i = tid; i < NBUCK; i += 256) h[i] = 0;
    __syncthreads();
    int start = vb * CH;
    int count = p.E - start;
    if (count > CH) count = CH;
    for (int i = tid; i < count; i += 256) atomicAdd(&h[p.dst[start + i] / p.R], 1);
    __syncthreads();
    for (int i = tid; i < NBUCK; i += 256) {
        int c = h[i];
        int base = c ? atomicAdd(&p.cursor[i], c) : 0;
        p.baseTbl[(size_t)vb * NBUCK + i] = base;
    }
}

// ---- phase: scatter into per-bucket fixed regions ----
__device__ void phase_scatter(const Params& p, int vb) {
    __shared__ int lcur[NBUCK];
    int tid = threadIdx.x;
    __syncthreads();  // LDS reuse guard
    for (int i = tid; i < NBUCK; i += 256)
        lcur[i] = i * CAP + p.baseTbl[(size_t)vb * NBUCK + i];
    __syncthreads();
    int start = vb * CH;
    int count = p.E - start;
    if (count > CH) count = CH;
    for (int i = tid; i < count; i += 256) {
        int d = p.dst[start + i];
        int s = p.src[start + i];
        int b = d / p.R;
        int r = atomicAdd(&lcur[b], 1);
        p.pairs[r] = ((unsigned long long)(unsigned)s << 32) | (unsigned)d;
    }
}

// ---- phase: per-bucket CSR build (LDS-staged) ----
__device__ void phase_csr(const Params& p, int b) {
    __shared__ unsigned long long stage[2048];
    __shared__ int h[256];
    __shared__ int loffs[256];
    __shared__ int cur[256];
    int tid = threadIdx.x;
    __syncthreads();  // LDS reuse guard
    int nodeBase = b * p.R;
    int beg = b * CAP;
    int len = p.cursor[b];
    int sl = len < 2048 ? len : 2048;
    for (int i = tid; i < sl; i += 256) stage[i] = p.pairs[beg + i];
    h[tid] = 0;
    __syncthreads();
    for (int i = tid; i < len; i += 256) {
        unsigned long long pr = (i < 2048) ? stage[i] : p.pairs[beg + i];
        atomicAdd(&h[(int)(pr & 0xffffffffull) - nodeBase], 1);
    }
    __syncthreads();
    int v = h[tid];
    loffs[tid] = v;
    __syncthreads();
    for (int off = 1; off < 256; off <<= 1) {
        int xv = (tid >= off) ? loffs[tid - off] : 0;
        __syncthreads();
        loffs[tid] += xv;
        __syncthreads();
    }
    int excl = loffs[tid] - v;
    cur[tid] = excl;
    int node = nodeBase + tid;
    if (tid < p.R && node < p.N) {
        p.counts[node] = v;
        p.offs[node] = beg + excl;
        p.dinv[node] = rsqrtf((float)v + 1.0f);  // +1 self-loop
    }
    __syncthreads();
    for (int i = tid; i < len; i += 256) {
        unsigned long long pr = (i < 2048) ? stage[i] : p.pairs[beg + i];
        int d = (int)(pr & 0xffffffffull) - nodeBase;
        int s = (int)(pr >> 32);
        int r = atomicAdd(&cur[d], 1);
        p.ssrc[beg + r] = s;
    }
}

// ---- phase: agg64 (8-lane group per node) ----
__device__ void phase_agg64(const Params& p, int vb) {
    const float4* hrow4 = (const float4*)p.h;
    float4* out4 = (float4*)p.out1;
    int tid = threadIdx.x;
    int lane = tid & 63;
    int l  = tid & 7;
    int gb = lane & 56;
    int node = vb * 32 + (tid >> 3);
    if (node >= p.N) return;
    int beg = p.offs[node], cnt = p.counts[node];
    float a[8];
#pragma unroll
    for (int j = 0; j < 8; ++j) a[j] = 0.f;
    for (int base = 0; base < cnt; base += 8) {
        int pos = base + l;
        int idx = 0;
        float dv = 0.0f;
        if (pos < cnt) {
            idx = p.ssrc[beg + pos];
            dv  = p.dinv[idx];
        }
#pragma unroll
        for (int j = 0; j < 8; ++j) {
            int   s  = __shfl(idx, gb | j, 64);
            float nv = __shfl(dv, gb | j, 64);
            float4 raw = hrow4[(size_t)s * 8 + l];
            float f[8];
            unpack8(raw, f);
#pragma unroll
            for (int d = 0; d < 8; ++d) a[d] = fmaf(f[d], nv, a[d]);
        }
    }
    float dd = p.dinv[node];
    float4 sraw = hrow4[(size_t)node * 8 + l];
    float sf[8];
    unpack8(sraw, sf);
    __half2 pk[4];
#pragma unroll
    for (int i = 0; i < 4; ++i) {
        float rx = fmaxf(dd * (a[2 * i] + sf[2 * i] * dd) + p.b1[8 * l + 2 * i], 0.0f);
        float ry = fmaxf(dd * (a[2 * i + 1] + sf[2 * i + 1] * dd) + p.b1[8 * l + 2 * i + 1], 0.0f);
        pk[i] = __floats2half2_rn(rx, ry);
    }
    out4[(size_t)node * 8 + l] = *(const float4*)pk;
}

// ---- phase: agg32 (4-lane group per node) -> fp32 out ----
__device__ void phase_agg32(const Params& p, int vb) {
    const float4* hrow4 = (const float4*)p.h2;
    float4* out4 = (float4*)p.out;
    int tid = threadIdx.x;
    int lane = tid & 63;
    int l  = tid & 3;
    int gb = lane & 60;
    int node = vb * 64 + (tid >> 2);
    if (node >= p.N) return;
    int beg = p.offs[node], cnt = p.counts[node];
    float a[8];
#pragma unroll
    for (int j = 0; j < 8; ++j) a[j] = 0.f;
    for (int base = 0; base < cnt; base += 4) {
        int pos = base + l;
        int idx = 0;
        float dv = 0.0f;
        if (pos < cnt) {
            idx = p.ssrc[beg + pos];
            dv  = p.dinv[idx];
        }
#pragma unroll
        for (int j = 0; j < 4; ++j) {
            int   s  = __shfl(idx, gb | j, 64);
            float nv = __shfl(dv, gb | j, 64);
            float4 raw = hrow4[(size_t)s * 4 + l];
            float f[8];
            unpack8(raw, f);
#pragma unroll
            for (int d = 0; d < 8; ++d) a[d] = fmaf(f[d], nv, a[d]);
        }
    }
    float dd = p.dinv[node];
    float4 sraw = hrow4[(size_t)node * 4 + l];
    float sf[8];
    unpack8(sraw, sf);
    float r[8];
#pragma unroll
    for (int j = 0; j < 8; ++j)
        r[j] = dd * (a[j] + sf[j] * dd) + p.b2[8 * l + j];
    out4[(size_t)node * 8 + 2 * l + 0] = make_float4(r[0], r[1], r[2], r[3]);
    out4[(size_t)node * 8 + 2 * l + 1] = make_float4(r[4], r[5], r[6], r[7]);
}

// ---- single cooperative kernel: all phases grid-stride, no early returns before last sync ----
__global__ __launch_bounds__(256, 2) void mega_kernel(Params p) {
    cg::grid_group grid = cg::this_grid();
    // Phase A: hist+reserve | gemm1
    for (int vb = blockIdx.x; vb < VTOT; vb += gridDim.x) {
        if (vb < p.HB) phase_hist(p, vb);
        else gemm1_body(p.x, p.W1, p.h, p.N, p.ntiles, vb - p.HB, VTOT - p.HB);
    }
    grid.sync();
    // Phase B: scatter
    for (int vb = blockIdx.x; vb < p.HB; vb += gridDim.x) phase_scatter(p, vb);
    grid.sync();
    // Phase C: CSR build
    for (int b = blockIdx.x; b < NBUCK; b += gridDim.x) phase_csr(p, b);
    grid.sync();
    // Phase D: agg64
    int nvb64 = (p.N + 31) >> 5;
    for (int vb = blockIdx.x; vb < nvb64; vb += gridDim.x) phase_agg64(p, vb);
    grid.sync();
    // Phase E: gemm2
    gemm2_body(p.out1, p.W2, p.h2, p.N, p.ntiles, blockIdx.x, gridDim.x);
    grid.sync();
    // Phase F: agg32
    int nvb32 = (p.N + 63) >> 6;
    for (int vb = blockIdx.x; vb < nvb32; vb += gridDim.x) phase_agg32(p, vb);
}

// ---- fallback wrappers (regular dispatches, same bodies) ----
__global__ __launch_bounds__(256) void k_phaseA(Params p) {
    int vb = blockIdx.x;
    if (vb < p.HB) phase_hist(p, vb);
    else gemm1_body(p.x, p.W1, p.h, p.N, p.ntiles, vb - p.HB, VTOT - p.HB);
}
__global__ __launch_bounds__(256) void k_scatter(Params p) { phase_scatter(p, blockIdx.x); }
__global__ __launch_bounds__(256) void k_csr(Params p) { phase_csr(p, blockIdx.x); }
__global__ __launch_bounds__(256) void k_agg64(Params p) { phase_agg64(p, blockIdx.x); }
__global__ __launch_bounds__(256) void k_gemm2(Params p) {
    gemm2_body(p.out1, p.W2, p.h2, p.N, p.ntiles, blockIdx.x, gridDim.x);
}
__global__ __launch_bounds__(256) void k_agg32(Params p) { phase_agg32(p, blockIdx.x); }

// ---------------- launch ----------------

extern "C" void kernel_launch(void* const* d_in, const int* in_sizes, int n_in,
                              void* d_out, int out_size, void* d_ws, size_t ws_size,
                              hipStream_t stream) {
    const float* x  = (const float*)d_in[0];
    const int*   ei = (const int*)d_in[1];
    const float* W1 = (const float*)d_in[2];
    const float* b1 = (const float*)d_in[3];
    const float* W2 = (const float*)d_in[4];
    const float* b2 = (const float*)d_in[5];

    const int N = in_sizes[0] / 64;   // 100000
    const int E = in_sizes[1] / 2;    // 1200000

    const int Npad = (N + 1023) & ~1023;      // 100352
    const int R    = (N + NBUCK - 1) / NBUCK; // 196
    const int HB   = (E + CH - 1) / CH;       // 293

    // workspace layout (all chunks 16B multiples)
    char* w = (char*)d_ws;
    unsigned long long* pairs = (unsigned long long*)w;  w += (size_t)NBUCK * CAP * 8;
    int*   ssrc    = (int*)w;                            w += (size_t)NBUCK * CAP * 4;
    int*   counts  = (int*)w;                            w += (size_t)Npad * 4;
    int*   offs    = (int*)w;                            w += (size_t)Npad * 4;
    float* dinv    = (float*)w;                          w += (size_t)Npad * 4;
    int*   baseTbl = (int*)w;                            w += (size_t)HB * NBUCK * 4;
    int*   cursor  = (int*)w;                            w += (size_t)(NBUCK + 4) * 4;
    __half* h    = (__half*)w;                           w += (size_t)N * 64 * 2;
    __half* out1 = (__half*)w;                           w += (size_t)N * 64 * 2;
    __half* h2   = h;  // reuses h buffer

    hipMemsetAsync(cursor, 0, NBUCK * sizeof(int), stream);

    Params p;
    p.src = ei;
    p.dst = ei + E;
    p.x = x; p.W1 = W1; p.b1 = b1; p.W2 = W2; p.b2 = b2;
    p.out = (float*)d_out;
    p.baseTbl = baseTbl; p.cursor = cursor;
    p.pairs = pairs; p.ssrc = ssrc;
    p.counts = counts; p.offs = offs; p.dinv = dinv;
    p.h = h; p.out1 = out1; p.h2 = h2;
    p.N = N; p.E = E; p.R = R; p.HB = HB;
    p.ntiles = (N + 15) / 16;

    // occupancy-derived cooperative grid (capture-safe host query)
    int occ = 0;
    hipOccupancyMaxActiveBlocksPerMultiprocessor(&occ, mega_kernel, 256, 0);
    hipError_t err = hipErrorUnknown;
    if (occ > 0) {
        int grid = occ * 256;  // 256 CUs on MI355X
        if (grid > VTOT) grid = VTOT;
        void* args[] = {&p};
        err = hipLaunchCooperativeKernel((const void*)mega_kernel, dim3(grid), dim3(256),
                                         args, 0, stream);
    }
    if (err != hipSuccess) {
        // deterministic fallback: same phases as regular dispatches
        k_phaseA<<<VTOT, 256, 0, stream>>>(p);
        k_scatter<<<HB, 256, 0, stream>>>(p);
        k_csr<<<NBUCK, 256, 0, stream>>>(p);
        k_agg64<<<(N + 31) / 32, 256, 0, stream>>>(p);
        k_gemm2<<<782, 256, 0, stream>>>(p);
        k_agg32<<<(N + 63) / 64, 256, 0, stream>>>(p);
    }
}

// Round 14
// 196.559 us; speedup vs baseline: 2.1391x; 2.1391x over previous
//
#include <hip/hip_runtime.h>
#include <hip/hip_fp16.h>

#define NBUCK 512   // dst-range buckets; R = ceil(N/NBUCK) <= 256
#define CH    4096  // edges per hist/scatter block
#define CAP   4096  // pairs capacity per bucket (mean fill ~2344, 36 sigma headroom)
#define VTOT  1024  // K1 grid: HB hist blocks + (VTOT-HB) gemm1 blocks

typedef _Float16 half8 __attribute__((ext_vector_type(8)));
typedef float floatx4 __attribute__((ext_vector_type(4)));

__device__ inline void unpack8(const float4& raw, float* f) {
    const __half2* p = (const __half2*)&raw;
#pragma unroll
    for (int i = 0; i < 4; ++i) {
        float2 t = __half22float2(p[i]);
        f[2 * i] = t.x;
        f[2 * i + 1] = t.y;
    }
}

// ---------------- K1: per-block dst histogram + atomic chunk reserve  ||  gemm1 ----------------
// blocks [0,HB): histogram CH edges, reserve contiguous space in bucket regions via cursor.
// blocks [HB,VTOT): X(M x 64) fp32 @ W1(64 x 64) -> h fp16 (MFMA, no LDS).

__global__ __launch_bounds__(256) void k_phaseA(
    const int* __restrict__ dst, int* __restrict__ baseTbl, int* __restrict__ cursor,
    const float* __restrict__ X, const float* __restrict__ W1, __half* __restrict__ H,
    int M, int ntiles, int E, int R, int HB) {
    int blk = blockIdx.x;
    if (blk < HB) {
        __shared__ int h[NBUCK];
        int tid = threadIdx.x;
        for (int i = tid; i < NBUCK; i += 256) h[i] = 0;
        __syncthreads();
        int start = blk * CH;
        int count = E - start;
        if (count > CH) count = CH;
        for (int i = tid; i < count; i += 256) atomicAdd(&h[dst[start + i] / R], 1);
        __syncthreads();
        for (int i = tid; i < NBUCK; i += 256) {
            int c = h[i];
            int base = c ? atomicAdd(&cursor[i], c) : 0;
            baseTbl[(size_t)blk * NBUCK + i] = base;
        }
    } else {
        const int GB = VTOT - HB;
        const int vblk = blk - HB;
        const int lane = threadIdx.x & 63;
        const int wid  = threadIdx.x >> 6;
        const int q    = lane >> 4;
        const int m    = lane & 15;

        half8 bfrag[2][4];
#pragma unroll
        for (int s = 0; s < 2; ++s)
#pragma unroll
            for (int c = 0; c < 4; ++c)
#pragma unroll
                for (int j = 0; j < 8; ++j)
                    bfrag[s][c][j] = (_Float16)W1[(s * 32 + q * 8 + j) * 64 + c * 16 + m];

        for (int tile = vblk * 4 + wid; tile < ntiles; tile += GB * 4) {
            int rowBase = tile * 16;
            int rowA = rowBase + m;
            if (rowA > M - 1) rowA = M - 1;
            const float4* Xr = (const float4*)(X + (size_t)rowA * 64);
            half8 afrag[2];
#pragma unroll
            for (int s = 0; s < 2; ++s) {
                float4 v0 = Xr[s * 8 + q * 2 + 0];
                float4 v1 = Xr[s * 8 + q * 2 + 1];
                afrag[s][0] = (_Float16)v0.x; afrag[s][1] = (_Float16)v0.y;
                afrag[s][2] = (_Float16)v0.z; afrag[s][3] = (_Float16)v0.w;
                afrag[s][4] = (_Float16)v1.x; afrag[s][5] = (_Float16)v1.y;
                afrag[s][6] = (_Float16)v1.z; afrag[s][7] = (_Float16)v1.w;
            }
            floatx4 acc[4];
#pragma unroll
            for (int c = 0; c < 4; ++c) acc[c] = (floatx4){0.f, 0.f, 0.f, 0.f};
#pragma unroll
            for (int s = 0; s < 2; ++s)
#pragma unroll
                for (int c = 0; c < 4; ++c)
                    acc[c] = __builtin_amdgcn_mfma_f32_16x16x32_f16(afrag[s], bfrag[s][c],
                                                                    acc[c], 0, 0, 0);
#pragma unroll
            for (int r = 0; r < 4; ++r) {
                int row = rowBase + q * 4 + r;
                if (row < M) {
#pragma unroll
                    for (int c = 0; c < 4; ++c)
                        H[(size_t)row * 64 + c * 16 + m] = __float2half(acc[c][r]);
                }
            }
        }
    }
}

// ---------------- K2: single-pass scatter into per-bucket fixed regions ----------------

__global__ __launch_bounds__(256) void k_scatter(
    const int* __restrict__ src, const int* __restrict__ dst, const int* __restrict__ baseTbl,
    unsigned long long* __restrict__ pairs, int E, int R) {
    __shared__ int lcur[NBUCK];
    int blk = blockIdx.x, tid = threadIdx.x;
    for (int i = tid; i < NBUCK; i += 256)
        lcur[i] = i * CAP + baseTbl[(size_t)blk * NBUCK + i];
    __syncthreads();
    int start = blk * CH;
    int count = E - start;
    if (count > CH) count = CH;
    for (int i = tid; i < count; i += 256) {
        int d = dst[start + i];
        int s = src[start + i];
        int b = d / R;
        int r = atomicAdd(&lcur[b], 1);
        pairs[r] = ((unsigned long long)(unsigned)s << 32) | (unsigned)d;
    }
}

// ---------------- K3: per-bucket CSR build (LDS-staged) ----------------

__global__ __launch_bounds__(256) void k_csr(
    const unsigned long long* __restrict__ pairs, const int* __restrict__ cursor,
    int* __restrict__ counts, int* __restrict__ offs, float* __restrict__ dinv,
    int* __restrict__ ssrc, int N, int R) {
    __shared__ unsigned long long stage[3072];
    __shared__ int h[256];
    __shared__ int loffs[256];
    __shared__ int cur[256];
    int b = blockIdx.x, tid = threadIdx.x;
    int nodeBase = b * R;
    int beg = b * CAP;
    int len = cursor[b];
    int sl = len < 3072 ? len : 3072;
    for (int i = tid; i < sl; i += 256) stage[i] = pairs[beg + i];
    h[tid] = 0;
    __syncthreads();
    for (int i = tid; i < len; i += 256) {
        unsigned long long pr = (i < 3072) ? stage[i] : pairs[beg + i];
        atomicAdd(&h[(int)(pr & 0xffffffffull) - nodeBase], 1);
    }
    __syncthreads();
    int v = h[tid];
    loffs[tid] = v;
    __syncthreads();
    for (int off = 1; off < 256; off <<= 1) {
        int xv = (tid >= off) ? loffs[tid - off] : 0;
        __syncthreads();
        loffs[tid] += xv;
        __syncthreads();
    }
    int excl = loffs[tid] - v;
    cur[tid] = excl;
    int node = nodeBase + tid;
    if (tid < R && node < N) {
        counts[node] = v;
        offs[node] = beg + excl;
        dinv[node] = rsqrtf((float)v + 1.0f);  // +1 self-loop
    }
    __syncthreads();
    for (int i = tid; i < len; i += 256) {
        unsigned long long pr = (i < 3072) ? stage[i] : pairs[beg + i];
        int d = (int)(pr & 0xffffffffull) - nodeBase;
        int s = (int)(pr >> 32);
        int r = atomicAdd(&cur[d], 1);
        ssrc[beg + r] = s;
    }
}

// ---------------- K4: agg64 (8-lane group per node) + fused layer-2 GEMV ----------------
// row = relu( dinv[n]*( sum h[s]*dinv[s] + h[n]*dinv[n] ) + b1 )   (fp32, in group registers)
// h2[n][j] = sum_d row[d] * W2[d][j]   (register GEMV via intra-group shfl; no LDS/sync)

__global__ __launch_bounds__(256) void k_agg64gemv(
    const float4* __restrict__ hrow4, const int* __restrict__ ssrc,
    const int* __restrict__ offs, const int* __restrict__ counts,
    const float* __restrict__ dinv, const float* __restrict__ b1,
    const float* __restrict__ W2, __half* __restrict__ h2, int N) {
    int tid  = threadIdx.x;
    int lane = tid & 63;
    int l    = tid & 7;            // lane within 8-lane group
    int gb   = lane & 56;          // group base lane within wave
    int node = blockIdx.x * 32 + (tid >> 3);
    if (node >= N) return;         // shfl sources stay within own group -> safe
    int beg = offs[node], cnt = counts[node];
    float a[8];
#pragma unroll
    for (int j = 0; j < 8; ++j) a[j] = 0.f;
    for (int base = 0; base < cnt; base += 8) {
        int pos = base + l;
        int idx = 0;
        float dv = 0.0f;
        if (pos < cnt) {
            idx = ssrc[beg + pos];
            dv  = dinv[idx];
        }
#pragma unroll
        for (int j = 0; j < 8; ++j) {
            int   s  = __shfl(idx, gb | j, 64);
            float nv = __shfl(dv, gb | j, 64);
            float4 raw = hrow4[(size_t)s * 8 + l];
            float f[8];
            unpack8(raw, f);
#pragma unroll
            for (int d = 0; d < 8; ++d) a[d] = fmaf(f[d], nv, a[d]);
        }
    }
    float dd = dinv[node];
    float4 sraw = hrow4[(size_t)node * 8 + l];
    float sf[8];
    unpack8(sraw, sf);
    float r[8];
#pragma unroll
    for (int j = 0; j < 8; ++j)
        r[j] = fmaxf(dd * (a[j] + sf[j] * dd) + b1[8 * l + j], 0.0f);

    // fused GEMV: lane l produces h2[n][4l..4l+3]
    float acc0 = 0.f, acc1 = 0.f, acc2 = 0.f, acc3 = 0.f;
#pragma unroll
    for (int slp = 0; slp < 8; ++slp) {
#pragma unroll
        for (int ddp = 0; ddp < 8; ++ddp) {
            float v = __shfl(r[ddp], gb | slp, 64);
            float4 w = *(const float4*)(W2 + (slp * 8 + ddp) * 32 + 4 * l);
            acc0 = fmaf(v, w.x, acc0);
            acc1 = fmaf(v, w.y, acc1);
            acc2 = fmaf(v, w.z, acc2);
            acc3 = fmaf(v, w.w, acc3);
        }
    }
    __half2 o01 = __floats2half2_rn(acc0, acc1);
    __half2 o23 = __floats2half2_rn(acc2, acc3);
    float2 pack;
    pack.x = *(const float*)&o01;
    pack.y = *(const float*)&o23;
    *(float2*)(h2 + (size_t)node * 32 + 4 * l) = pack;
}

// ---------------- K5: agg32 (4-lane group per node) -> fp32 out ----------------

__global__ __launch_bounds__(256) void k_agg32(
    const float4* __restrict__ hrow4, const int* __restrict__ ssrc,
    const int* __restrict__ offs, const int* __restrict__ counts,
    const float* __restrict__ dinv, const float* __restrict__ b2,
    float4* __restrict__ out4, int N) {
    int tid  = threadIdx.x;
    int lane = tid & 63;
    int l    = tid & 3;            // lane within 4-lane group
    int gb   = lane & 60;          // group base lane within wave
    int node = blockIdx.x * 64 + (tid >> 2);
    if (node >= N) return;
    int beg = offs[node], cnt = counts[node];
    float a[8];
#pragma unroll
    for (int j = 0; j < 8; ++j) a[j] = 0.f;
    for (int base = 0; base < cnt; base += 4) {
        int pos = base + l;
        int idx = 0;
        float dv = 0.0f;
        if (pos < cnt) {
            idx = ssrc[beg + pos];
            dv  = dinv[idx];
        }
#pragma unroll
        for (int j = 0; j < 4; ++j) {
            int   s  = __shfl(idx, gb | j, 64);
            float nv = __shfl(dv, gb | j, 64);
            float4 raw = hrow4[(size_t)s * 4 + l];
            float f[8];
            unpack8(raw, f);
#pragma unroll
            for (int d = 0; d < 8; ++d) a[d] = fmaf(f[d], nv, a[d]);
        }
    }
    float dd = dinv[node];
    float4 sraw = hrow4[(size_t)node * 4 + l];
    float sf[8];
    unpack8(sraw, sf);
    float r[8];
#pragma unroll
    for (int j = 0; j < 8; ++j)
        r[j] = dd * (a[j] + sf[j] * dd) + b2[8 * l + j];
    out4[(size_t)node * 8 + 2 * l + 0] = make_float4(r[0], r[1], r[2], r[3]);
    out4[(size_t)node * 8 + 2 * l + 1] = make_float4(r[4], r[5], r[6], r[7]);
}

// ---------------- launch ----------------

extern "C" void kernel_launch(void* const* d_in, const int* in_sizes, int n_in,
                              void* d_out, int out_size, void* d_ws, size_t ws_size,
                              hipStream_t stream) {
    const float* x  = (const float*)d_in[0];
    const int*   ei = (const int*)d_in[1];
    const float* W1 = (const float*)d_in[2];
    const float* b1 = (const float*)d_in[3];
    const float* W2 = (const float*)d_in[4];
    const float* b2 = (const float*)d_in[5];

    const int N = in_sizes[0] / 64;   // 100000
    const int E = in_sizes[1] / 2;    // 1200000
    const int* src = ei;
    const int* dst = ei + E;

    const int Npad = (N + 1023) & ~1023;      // 100352
    const int R    = (N + NBUCK - 1) / NBUCK; // 196 (<= 256)
    const int HB   = (E + CH - 1) / CH;       // 293 (< VTOT)

    // workspace layout (all chunks 16B multiples)
    char* w = (char*)d_ws;
    unsigned long long* pairs = (unsigned long long*)w;  w += (size_t)NBUCK * CAP * 8;
    int*   ssrc    = (int*)w;                            w += (size_t)NBUCK * CAP * 4;
    int*   counts  = (int*)w;                            w += (size_t)Npad * 4;
    int*   offs    = (int*)w;                            w += (size_t)Npad * 4;
    float* dinv    = (float*)w;                          w += (size_t)Npad * 4;
    int*   baseTbl = (int*)w;                            w += (size_t)HB * NBUCK * 4;
    int*   cursor  = (int*)w;                            w += (size_t)(NBUCK + 4) * 4;
    __half* h  = (__half*)w;                             w += (size_t)N * 64 * 2;  // N*64 fp16
    __half* h2 = (__half*)w;                             w += (size_t)N * 32 * 2;  // N*32 fp16 (NOT aliasing h)

    const int ntiles = (N + 15) / 16;  // 6250

    hipMemsetAsync(cursor, 0, NBUCK * sizeof(int), stream);

    // K1: dst histogram + chunk reserve || layer-1 GEMM
    k_phaseA<<<VTOT, 256, 0, stream>>>(dst, baseTbl, cursor, x, W1, h, N, ntiles, E, R, HB);
    // K2: single-pass scatter into bucket regions
    k_scatter<<<HB, 256, 0, stream>>>(src, dst, baseTbl, pairs, E, R);
    // K3: per-bucket CSR build
    k_csr<<<NBUCK, 256, 0, stream>>>(pairs, cursor, counts, offs, dinv, ssrc, N, R);
    // K4: layer-1 aggregation + relu + fused layer-2 linear -> h2
    k_agg64gemv<<<(N + 31) / 32, 256, 0, stream>>>((const float4*)h, ssrc, offs, counts, dinv,
                                                   b1, W2, h2, N);
    // K5: layer-2 aggregation -> out
    k_agg32<<<(N + 63) / 64, 256, 0, stream>>>((const float4*)h2, ssrc, offs, counts, dinv, b2,
                                               (float4*)d_out, N);
}